// Round 19
// baseline (132.552 us; speedup 1.0000x reference)
//
#include <hip/hip_runtime.h>

#define N_NODES 20000
#define N_EDGES 600000
#define HID 128
#define NB N_NODES
#define NBP (NB + 8)                // X1 row stride incl. zero row at index NB
#define NBLK64 313                  // ceil(20000/64)
#define BPG 160                     // partition blocks per graph
#define CHUNK (N_EDGES / BPG)       // 3750
#define NBUCK 157                   // ceil(20000/128) dst-buckets
#define BSH 7                       // bucket = dst >> 7
#define COLCAP 760832               // 600000 + 157*1024 + 64 slack

typedef unsigned int uint32;
typedef __attribute__((ext_vector_type(8))) short bf16x8v;   // 8 bf16 in 4 VGPRs
typedef __attribute__((ext_vector_type(4))) float f32x4;
typedef __attribute__((ext_vector_type(2))) float f32x2;

// ---------------- workspace layout (4-byte words), NO aliasing ----------------
#define P_OFF     0                 // 3*600000 u32 packed (src | (dst&127)<<16)
#define BCNT_OFF  1800000           // 3*160*157 u32 (raw counts)
#define BBASE_OFF 1875360           // 3*158 u32
#define X1_OFF    1875840           // x1 bf16-packed: 3*20008*64 (zero row at NB)
#define H2_OFF    5717376           // h2 bf16-packed: 3*20000*64
#define COL_OFF   9557376           // 3*COLCAP u32 (byte offsets src*256)
#define RPE_OFF   11839872          // 3*20000*2 int (beg, padded end per node)
#define GSUM_OFF  11959872          // 3*128 f32
#define TS_OFF    11960256          // 128 f32 sorted breakpoints
#define UV_OFF    11960384          // 129 x (U[128],V[128]) f32 = 33024
#define W21P_OFF  11993408          // 128*128 bf16 frag-packed = 8192 words
#define W22P_OFF  12001600          // 8192 words
// end 12,009,792 words = 48.0 MB

static __device__ inline unsigned short f2bf(float f) {
    uint32 u = __float_as_uint(f);
    return (unsigned short)((u + 0x7fffu + ((u >> 16) & 1u)) >> 16);
}
static __device__ inline uint32 pack2(float a, float b) {
    return (uint32)f2bf(a) | ((uint32)f2bf(b) << 16);
}
static __device__ inline f32x2 unpk(uint32 v) {
    f32x2 r;
    r.x = __uint_as_float(v << 16);
    r.y = __uint_as_float(v & 0xffff0000u);
    return r;
}

// ---- fused launch 1: bhist (blocks x<160) + prep (UV tables / frag-pack) ----
__launch_bounds__(512)
__global__ void bhist_prep_kernel(const int* __restrict__ ea, const int* __restrict__ ep,
                                  const int* __restrict__ en, uint32* __restrict__ bcnt,
                                  const float* __restrict__ W11, const float* __restrict__ b11,
                                  const float* __restrict__ W12, const float* __restrict__ b12,
                                  const float* __restrict__ W21, const float* __restrict__ W22,
                                  float* __restrict__ ts, float* __restrict__ UV,
                                  uint32* __restrict__ W21p, uint32* __restrict__ W22p,
                                  float* __restrict__ gsum) {
    int tid = threadIdx.x;
    if (blockIdx.x < BPG) {
        // ---------- bucket histogram ----------
        __shared__ uint32 c[NBUCK];
        int g = blockIdx.y, blk = blockIdx.x;
        const int* e = (g == 0) ? ea : (g == 1) ? ep : en;
        if (tid < NBUCK) c[tid] = 0;
        __syncthreads();
        int base = blk * CHUNK;
        for (int i = tid; i < CHUNK; i += 512)
            atomicAdd(&c[e[N_EDGES + base + i] >> BSH], 1u);
        __syncthreads();
        if (tid < NBUCK) bcnt[((size_t)g * BPG + blk) * NBUCK + tid] = c[tid];
        return;
    }
    int p = (blockIdx.x - BPG) * 3 + blockIdx.y;   // 0..17
    if (p >= 16) return;
    if (p < 8) {
        // ---------- UV tables via parallel scan (512-thread variant) ----------
        __shared__ float w12s[128][16];
        __shared__ float du[128][16];
        __shared__ float dv[128][16];
        __shared__ float pu[16][16], pv[16][16];
        __shared__ float bu[16][16], bv[16][16];
        __shared__ float wsh[128], bsh[128], tss[128], tsh[128];
        __shared__ int osh[128];
        int c0 = p * 16;
        if (tid < 128) {
            float w = W11[tid], b = b11[tid];
            wsh[tid] = w; bsh[tid] = b;
            tsh[tid] = (w != 0.0f) ? (-b / w) : 3.0e38f;
        }
        {
            int r0 = tid >> 4, cc2 = tid & 15;     // r0 0..31
            for (int r = r0; r < 128; r += 32)
                w12s[r][cc2] = W12[r * HID + c0 + cc2];
        }
        __syncthreads();
        if (tid < 128) {
            float t = tsh[tid];
            int rank = 0;
            for (int j = 0; j < 128; ++j) {
                float tj = tsh[j];
                if (tj < t || (tj == t && j < tid)) ++rank;
            }
            tss[rank] = t; osh[rank] = tid;
        }
        __syncthreads();
        if (p == 0 && tid < 128) ts[tid] = tss[tid];
        int c = tid & 15, t = tid >> 4;            // t 0..31; only t<16 active
        if (t < 16) {
            float su = 0.f, sv = 0.f;
#pragma unroll
            for (int m = 0; m < 8; ++m) {
                int j = t * 8 + m;
                int k = osh[j];
                float wk = wsh[k], bk = bsh[k], w12 = w12s[k][c];
                float sg = (wk > 0.f) ? 1.f : ((wk < 0.f) ? -1.f : 0.f);
                du[j][c] = sg * wk * w12;
                dv[j][c] = sg * bk * w12;
                float wb = wsh[j], bb = bsh[j], w12b = w12s[j][c];
                if (wb < 0.f)                     { su += wb * w12b; sv += bb * w12b; }
                else if (wb == 0.f && bb > 0.f)   { sv += bb * w12b; }
            }
            bu[t][c] = su; bv[t][c] = sv;
        }
        __syncthreads();
        if (t < 16) {
            float ru = 0.f, rv = 0.f;
#pragma unroll
            for (int m = 0; m < 8; ++m) {
                int j = t * 8 + m;
                ru += du[j][c]; du[j][c] = ru;
                rv += dv[j][c]; dv[j][c] = rv;
            }
            pu[t][c] = ru; pv[t][c] = rv;
        }
        __syncthreads();
        if (t == 0) {                              // col leader
            float baseu = 0.f;
            float basev = b12[c0 + c];             // bias included
            for (int q = 0; q < 16; ++q) { baseu += bu[q][c]; basev += bv[q][c]; }
            float ou = baseu, ov = basev;
            for (int q = 0; q < 16; ++q) {
                float tu = pu[q][c], tv = pv[q][c];
                pu[q][c] = ou; pv[q][c] = ov;
                ou += tu; ov += tv;
            }
            UV[c0 + c] = baseu; UV[128 + c0 + c] = basev;
        }
        __syncthreads();
        if (t < 16) {
            float offu = pu[t][c], offv = pv[t][c];
#pragma unroll
            for (int m = 0; m < 8; ++m) {
                int j = t * 8 + m;
                UV[(j + 1) * 256 + c0 + c]       = offu + du[j][c];
                UV[(j + 1) * 256 + 128 + c0 + c] = offv + dv[j][c];
            }
        }
    } else if (tid < 256) {
        // ---------- frag-pack W21/W22 ----------
        int idx = (p - 8) * 256 + tid;             // 0..2047
        int tt = idx >> 9, c = (idx >> 6) & 7, l = idx & 63;
        int kbase = tt * 32 + (l >> 4) * 8;
        int colv = c * 16 + (l & 15);
#pragma unroll
        for (int jw = 0; jw < 4; ++jw) {
            float f0 = W21[(kbase + 2 * jw) * HID + colv];
            float f1 = W21[(kbase + 2 * jw + 1) * HID + colv];
            W21p[idx * 4 + jw] = pack2(f0, f1);
            f0 = W22[(kbase + 2 * jw) * HID + colv];
            f1 = W22[(kbase + 2 * jw + 1) * HID + colv];
            W22p[idx * 4 + jw] = pack2(f0, f1);
        }
        if (p == 8)
            for (int i = tid; i < 384; i += 256) gsum[i] = 0.0f;
    }
}

// ---- bucket phase C (fused with scan): partition edges into bucket-major P ----
__launch_bounds__(512)
__global__ void bpart_kernel(const int* __restrict__ ea, const int* __restrict__ ep,
                             const int* __restrict__ en, const uint32* __restrict__ bcnt,
                             uint32* __restrict__ bbase, uint32* __restrict__ P) {
    __shared__ uint32 cur[NBUCK];
    __shared__ uint32 totS[NBUCK];
    __shared__ uint32 sbase[NBUCK + 1];
    int g = blockIdx.y, blk = blockIdx.x, tid = threadIdx.x;
    const int* e = (g == 0) ? ea : (g == 1) ? ep : en;
    if (tid < NBUCK) {
        uint32 myoff = 0, tot = 0;
        const uint32* bc = bcnt + (size_t)g * BPG * NBUCK + tid;
        for (int k = 0; k < BPG; ++k) {
            uint32 v = bc[(size_t)k * NBUCK];
            if (k < blk) myoff += v;
            tot += v;
        }
        cur[tid] = myoff;
        totS[tid] = tot;
    }
    __syncthreads();
    if (tid == 0) {
        uint32 run = 0;
        for (int b2 = 0; b2 < NBUCK; ++b2) { sbase[b2] = run; run += totS[b2]; }
        sbase[NBUCK] = run;   // == N_EDGES
    }
    __syncthreads();
    if (tid < NBUCK) cur[tid] += sbase[tid];
    if (blk == 0 && tid <= NBUCK) bbase[g * 158 + tid] = sbase[tid];
    __syncthreads();
    int base = blk * CHUNK;
    uint32* Pg = P + (size_t)g * N_EDGES;
    for (int i = tid; i < CHUNK; i += 512) {
        int src = e[base + i];
        int dst = e[N_EDGES + base + i];
        uint32 pos = atomicAdd(&cur[dst >> BSH], 1u);
        Pg[pos] = (uint32)src | ((uint32)(dst & 127) << 16);
    }
}

// ---- bucket phase D fused with L1: per-bucket CSR with SELF-EDGE prepended,
//      pad-to-8 WITH sentinel fill (-> zero row), node-major rpe (padded end),
//      + scalar aggregation + pattern-table MLP1 -> X1 ----
__launch_bounds__(256)
__global__ void bcsr_l1_kernel(const uint32* __restrict__ bbase, const uint32* __restrict__ P,
                               const float* __restrict__ xa, const float* __restrict__ xp,
                               const float* __restrict__ xn,
                               const float* __restrict__ ts, const float* __restrict__ UV,
                               int* __restrict__ rpe, uint32* __restrict__ col,
                               uint32* __restrict__ X1) {
    __shared__ uint32 h[128];        // raw counts, then rank cursors
    __shared__ uint32 hraw[128];
    __shared__ uint32 pls[128];      // padded local scan (self+edges, x8)
    __shared__ uint32 wendS;
    __shared__ float accs[128];
    __shared__ float tsh[128];
    __shared__ int pat[128];
    int k = blockIdx.x, g = blockIdx.y, tid = threadIdx.x;
    const float* x = (g == 0) ? xa : (g == 1) ? xp : xn;
    int beg = (int)bbase[g * 158 + k], end = (int)bbase[g * 158 + k + 1];
    int size = end - beg;
    int wbase = beg + k * 1024;      // padded col window base
    int n0 = k * 128;
    int cnt_nodes = NB - n0; if (cnt_nodes > 128) cnt_nodes = 128;
    const uint32 ZOFFB = (uint32)NB << 8;
    if (tid < 128) { h[tid] = 0; accs[tid] = 0.0f; tsh[tid] = ts[tid]; }
    __syncthreads();
    const uint32* Pg = P + (size_t)g * N_EDGES + beg;
    for (int i = tid; i < size; i += 256)
        atomicAdd(&h[(Pg[i] >> 16) & 127], 1u);
    __syncthreads();
    if (tid == 0) {
        uint32 run = 0;
        for (int d = 0; d < 128; ++d) {
            hraw[d] = h[d];
            pls[d] = run;
            run += (h[d] + 8u) & ~7u;   // +1 self edge, pad to 8
        }
        wendS = (uint32)wbase + run;
    }
    __syncthreads();
    uint32* colg = col + (size_t)g * COLCAP;
    if (tid < cnt_nodes) {
        int node = n0 + tid;
        rpe[((size_t)g * NB + node) * 2]     = wbase + (int)pls[tid];
        rpe[((size_t)g * NB + node) * 2 + 1] = wbase + (int)(pls[tid] + ((hraw[tid] + 8u) & ~7u));
        colg[wbase + pls[tid]] = (uint32)node << 8;     // self edge first
        uint32 e0 = pls[tid] + 1u + hraw[tid];
        uint32 e1 = pls[tid] + ((hraw[tid] + 8u) & ~7u);
        for (uint32 q = e0; q < e1; ++q) colg[wbase + q] = ZOFFB;
    } else if (tid < 128) {
        uint32 e0 = pls[tid];
        uint32 e1 = pls[tid] + 8u;
        for (uint32 q = e0; q < e1; ++q) colg[wbase + q] = ZOFFB;
    }
    if (tid < 128) h[tid] = pls[tid] + 1u;   // rank cursors after self
    __syncthreads();
    for (int i = tid; i < size; i += 256) {
        uint32 w = Pg[i];
        int d = (w >> 16) & 127;
        int src = (int)(w & 0xffffu);
        uint32 r = atomicAdd(&h[d], 1u);
        colg[wbase + r] = (uint32)src << 8;   // byte offset src*256
        atomicAdd(&accs[d], x[src]);          // LDS float accumulation
    }
    if (k == 0 && tid < 64)                   // zero row for this graph
        *((uint32*)&X1[((size_t)g * NBP + NB) * 64] + tid) = 0u;
    if (k == NBUCK - 1 && tid < 64)           // tail slack fill (prefetch overrun)
        colg[wendS + tid] = ZOFFB;
    __syncthreads();
    if (tid < cnt_nodes) {
        float s = accs[tid] + x[n0 + tid];
        int lo = 0, hi = 128;
        while (lo < hi) { int mid = (lo + hi) >> 1; if (tsh[mid] < s) lo = mid + 1; else hi = mid; }
        pat[tid] = lo;
        accs[tid] = s;
    }
    __syncthreads();
    uint32* X1g = X1 + ((size_t)g * NBP + n0) * 64;
#pragma unroll 4
    for (int it = 0; it < 32; ++it) {
        int idx = it * 256 + tid;
        int d = idx >> 6, w = idx & 63;
        if (d < cnt_nodes) {
            const float* Up = UV + (size_t)pat[d] * 256;
            float s = accs[d];
            float2 u = *(const float2*)&Up[w * 2];
            float2 v = *(const float2*)&Up[128 + w * 2];
            float r0 = fmaxf(fmaf(s, u.x, v.x), 0.0f);
            float r1 = fmaxf(fmaf(s, u.y, v.y), 0.0f);
            X1g[(size_t)d * 64 + w] = pack2(r0, r1);
        }
    }
}

// ---- L2 aggregation: single launch, 3 phases x 2 tasks x 4 XCDs.
// EIGHT node-halves per wave (8 lanes each own 16B of the 128B half; no
// cross-lane reduction), self-edge in list, 4-deep pipelined, no guards. ----
__launch_bounds__(256)
__global__ void gather2_kernel(const int* __restrict__ rpe, const uint32* __restrict__ col,
                               const uint32* __restrict__ X1, uint32* __restrict__ H2) {
    int b = blockIdx.x;                        // 0..3767
    int xcd = b & 7, s = b >> 3;               // s 0..470
    int phase = s / 157, slot = s - phase * 157;
    const int gt[3][2] = {{0, 1}, {2, 2}, {0, 1}};
    const int ht[3][2] = {{0, 0}, {0, 1}, {1, 1}};
    int g = gt[phase][xcd >> 2];
    int h = ht[phase][xcd >> 2];
    int nb = slot * 4 + (xcd & 3);             // 0..627
    if (nb >= 625) return;
    int tid = threadIdx.x;
    int wave = tid >> 6, lane = tid & 63;
    int node = nb * 32 + wave * 8 + (lane >> 3);
    int w = lane & 7;                          // uint4 index within 128B half-row
    const uint32* colg = col + (size_t)g * COLCAP;
    int2 be = *(const int2*)&rpe[((size_t)g * NB + node) * 2];
    int beg = be.x, end = be.y;                // padded length (multiple of 8)
    const char* Bg = (const char*)(X1 + (size_t)g * NBP * 64) + h * 128 + w * 16;
    f32x2 A0 = {0.f, 0.f}, A1 = {0.f, 0.f}, A2 = {0.f, 0.f}, A3 = {0.f, 0.f};
    uint32 ca = colg[beg];
    uint32 cb = colg[beg + 1];
    uint32 cc = colg[beg + 2];
    uint32 cd = colg[beg + 3];
    for (int j = beg; j < end; j += 4) {
        uint32 c0 = ca, c1 = cb, c2 = cc, c3 = cd;
        ca = colg[j + 4];                      // prefetch (slack-covered)
        cb = colg[j + 5];
        cc = colg[j + 6];
        cd = colg[j + 7];
        uint4 v0 = *(const uint4*)(Bg + c0);
        uint4 v1 = *(const uint4*)(Bg + c1);
        uint4 v2 = *(const uint4*)(Bg + c2);
        uint4 v3 = *(const uint4*)(Bg + c3);
        A0 += unpk(v0.x); A1 += unpk(v0.y); A2 += unpk(v0.z); A3 += unpk(v0.w);
        A0 += unpk(v1.x); A1 += unpk(v1.y); A2 += unpk(v1.z); A3 += unpk(v1.w);
        A0 += unpk(v2.x); A1 += unpk(v2.y); A2 += unpk(v2.z); A3 += unpk(v2.w);
        A0 += unpk(v3.x); A1 += unpk(v3.y); A2 += unpk(v3.z); A3 += unpk(v3.w);
    }
    uint4 o;
    o.x = pack2(A0.x, A0.y); o.y = pack2(A1.x, A1.y);
    o.z = pack2(A2.x, A2.y); o.w = pack2(A3.x, A3.y);
    *(uint4*)&H2[(size_t)(g * NB + node) * 64 + h * 32 + w * 4] = o;
}

// ---- MFMA MLP2: x2 = relu(relu(h2@W21+b21)@W22+b22), pool-only ----
__launch_bounds__(256)
__global__ void mlp2_kernel(const uint32* __restrict__ H2,
                            const uint32* __restrict__ W21p, const float* __restrict__ b21,
                            const uint32* __restrict__ W22p, const float* __restrict__ b22,
                            float* __restrict__ gsum) {
    __shared__ uint32 tl[64 * 64];      // t tile, bf16, XOR-swizzled rows of 256B
    __shared__ float psum[HID];
    int g = blockIdx.y;
    int base = blockIdx.x * 64;
    int nvalid = NB - base; if (nvalid > 64) nvalid = 64;
    int tid = threadIdx.x;
    int wave = tid >> 6, l = tid & 63;
    int lq = l >> 4, lr = l & 15;
    if (tid < HID) psum[tid] = 0.0f;
    __syncthreads();

    f32x4 acc[8];
#pragma unroll
    for (int c = 0; c < 8; ++c) acc[c] = (f32x4){0.f, 0.f, 0.f, 0.f};
    int arow = wave * 16 + lr;
    int arowc = (arow < nvalid) ? arow : 0;
    const uint32* h2row = H2 + ((size_t)g * NB + base + arowc) * 64;
#pragma unroll
    for (int t = 0; t < 4; ++t) {
        uint4 av = *(const uint4*)&h2row[t * 16 + lq * 4];
        bf16x8v af = __builtin_bit_cast(bf16x8v, av);
#pragma unroll
        for (int c = 0; c < 8; ++c) {
            uint4 bv = *(const uint4*)&W21p[((t * 8 + c) * 64 + l) * 4];
            acc[c] = __builtin_amdgcn_mfma_f32_16x16x32_bf16(
                af, __builtin_bit_cast(bf16x8v, bv), acc[c], 0, 0, 0);
        }
    }
    unsigned short* tls = (unsigned short*)tl;
#pragma unroll
    for (int c = 0; c < 8; ++c) {
        int colv = c * 16 + lr;
        float bb = b21[colv];
#pragma unroll
        for (int q = 0; q < 4; ++q) {
            int row = wave * 16 + lq * 4 + q;
            float v = fmaxf(acc[c][q] + bb, 0.0f);
            int byte = row * 256 + ((colv * 2) ^ ((row & 7) << 4));
            tls[byte >> 1] = f2bf(v);
        }
    }
    f32x4 acc2[8];
#pragma unroll
    for (int c = 0; c < 8; ++c) acc2[c] = (f32x4){0.f, 0.f, 0.f, 0.f};
#pragma unroll
    for (int t = 0; t < 4; ++t) {
        int rbyte = arow * 256 + (((t * 64 + lq * 16)) ^ ((arow & 7) << 4));
        uint4 av = *(const uint4*)((const char*)tl + rbyte);
        bf16x8v af = __builtin_bit_cast(bf16x8v, av);
#pragma unroll
        for (int c = 0; c < 8; ++c) {
            uint4 bv = *(const uint4*)&W22p[((t * 8 + c) * 64 + l) * 4];
            acc2[c] = __builtin_amdgcn_mfma_f32_16x16x32_bf16(
                af, __builtin_bit_cast(bf16x8v, bv), acc2[c], 0, 0, 0);
        }
    }
#pragma unroll
    for (int c = 0; c < 8; ++c) {
        float bb = b22[c * 16 + lr];
        float s = 0.0f;
#pragma unroll
        for (int q = 0; q < 4; ++q) {
            int row = wave * 16 + lq * 4 + q;
            float v = fmaxf(acc2[c][q] + bb, 0.0f);
            s += (row < nvalid) ? v : 0.0f;
        }
        s += __shfl_xor(s, 16);
        s += __shfl_xor(s, 32);
        if (lq == 0) atomicAdd(&psum[c * 16 + lr], s);
    }
    __syncthreads();
    if (tid < HID) atomicAdd(&gsum[g * HID + tid], psum[tid]);
}

// ---- triplet head ----
__global__ void final_kernel(const float* __restrict__ gsum, const float* __restrict__ Wf,
                             const float* __restrict__ bf, float* __restrict__ out) {
    int tid = threadIdx.x;  // 384
    int g = tid >> 7;
    int o = tid & 127;
    float acc = bf[o];
    for (int k = 0; k < HID; ++k)
        acc += gsum[g * HID + k] * Wf[k * HID + o];
    out[g * HID + o] = acc;
}

extern "C" void kernel_launch(void* const* d_in, const int* in_sizes, int n_in,
                              void* d_out, int out_size, void* d_ws, size_t ws_size,
                              hipStream_t stream) {
    const float* xa = (const float*)d_in[0];
    const int*   ea = (const int*)d_in[1];
    const float* xp = (const float*)d_in[2];
    const int*   ep = (const int*)d_in[3];
    const float* xn = (const float*)d_in[4];
    const int*   en = (const int*)d_in[5];
    const float* W11 = (const float*)d_in[6];
    const float* b11 = (const float*)d_in[7];
    const float* W12 = (const float*)d_in[8];
    const float* b12 = (const float*)d_in[9];
    const float* W21 = (const float*)d_in[10];
    const float* b21 = (const float*)d_in[11];
    const float* W22 = (const float*)d_in[12];
    const float* b22 = (const float*)d_in[13];
    const float* Wf  = (const float*)d_in[14];
    const float* bf  = (const float*)d_in[15];

    float*  ws    = (float*)d_ws;
    uint32* P     = (uint32*)(ws + P_OFF);
    uint32* bcnt  = (uint32*)(ws + BCNT_OFF);
    uint32* bbase = (uint32*)(ws + BBASE_OFF);
    uint32* X1    = (uint32*)(ws + X1_OFF);
    uint32* H2    = (uint32*)(ws + H2_OFF);
    uint32* col   = (uint32*)(ws + COL_OFF);
    int*    rpe   = (int*)(ws + RPE_OFF);
    float*  gsum  = ws + GSUM_OFF;
    float*  ts    = ws + TS_OFF;
    float*  UV    = ws + UV_OFF;
    uint32* W21p  = (uint32*)(ws + W21P_OFF);
    uint32* W22p  = (uint32*)(ws + W22P_OFF);
    float*  out   = (float*)d_out;

    bhist_prep_kernel<<<dim3(BPG + 6, 3), 512, 0, stream>>>(
        ea, ep, en, bcnt, W11, b11, W12, b12, W21, W22, ts, UV, W21p, W22p, gsum);
    bpart_kernel<<<dim3(BPG, 3), 512, 0, stream>>>(ea, ep, en, bcnt, bbase, P);
    bcsr_l1_kernel<<<dim3(NBUCK, 3), 256, 0, stream>>>(bbase, P, xa, xp, xn, ts, UV, rpe, col, X1);
    gather2_kernel<<<3768, 256, 0, stream>>>(rpe, col, X1, H2);
    mlp2_kernel<<<dim3(NBLK64, 3), 256, 0, stream>>>(H2, W21p, b21, W22p, b22, gsum);
    final_kernel<<<1, 384, 0, stream>>>(gsum, Wf, bf, out);
}

// Round 20
// 125.624 us; speedup vs baseline: 1.0551x; 1.0551x over previous
//
#include <hip/hip_runtime.h>

#define N_NODES 20000
#define N_EDGES 600000
#define HID 128
#define NB N_NODES
#define NBP (NB + 8)                // X1 row stride incl. zero row at index NB
#define NBLK64 313                  // ceil(20000/64)
#define BPG 160                     // partition blocks per graph
#define CHUNK (N_EDGES / BPG)       // 3750
#define NBUCK 157                   // ceil(20000/128) dst-buckets
#define BSH 7                       // bucket = dst >> 7
#define COLCAP 760832               // 600000 + 157*1024 + 64 slack

typedef unsigned int uint32;
typedef __attribute__((ext_vector_type(8))) short bf16x8v;   // 8 bf16 in 4 VGPRs
typedef __attribute__((ext_vector_type(4))) float f32x4;
typedef __attribute__((ext_vector_type(2))) float f32x2;

// ---------------- workspace layout (4-byte words), NO aliasing ----------------
#define P_OFF     0                 // 3*600000 u32 packed (src | (dst&127)<<16)
#define BCNT_OFF  1800000           // 3*160*157 u32 (raw counts)
#define BBASE_OFF 1875360           // 3*158 u32
#define X1_OFF    1875840           // x1 bf16-packed: 3*20008*64 (zero row at NB)
#define H2_OFF    5717376           // h2 bf16-packed: 3*20000*64
#define COL_OFF   9557376           // 3*COLCAP u32 (byte offsets src*256)
#define RPE_OFF   11839872          // 3*20000*2 int (beg, padded end per node)
#define GSUM_OFF  11959872          // 3*128 f32
#define TS_OFF    11960256          // 128 f32 sorted breakpoints
#define UV_OFF    11960384          // 129 x (U[128],V[128]) f32 = 33024
#define W21P_OFF  11993408          // 128*128 bf16 frag-packed = 8192 words
#define W22P_OFF  12001600          // 8192 words
// end 12,009,792 words = 48.0 MB

static __device__ inline unsigned short f2bf(float f) {
    uint32 u = __float_as_uint(f);
    return (unsigned short)((u + 0x7fffu + ((u >> 16) & 1u)) >> 16);
}
static __device__ inline uint32 pack2(float a, float b) {
    return (uint32)f2bf(a) | ((uint32)f2bf(b) << 16);
}
static __device__ inline f32x2 unpk(uint32 v) {
    f32x2 r;
    r.x = __uint_as_float(v << 16);
    r.y = __uint_as_float(v & 0xffff0000u);
    return r;
}

// ---- fused launch 1: bhist (blocks x<160) + prep (UV tables / frag-pack) ----
__launch_bounds__(512)
__global__ void bhist_prep_kernel(const int* __restrict__ ea, const int* __restrict__ ep,
                                  const int* __restrict__ en, uint32* __restrict__ bcnt,
                                  const float* __restrict__ W11, const float* __restrict__ b11,
                                  const float* __restrict__ W12, const float* __restrict__ b12,
                                  const float* __restrict__ W21, const float* __restrict__ W22,
                                  float* __restrict__ ts, float* __restrict__ UV,
                                  uint32* __restrict__ W21p, uint32* __restrict__ W22p,
                                  float* __restrict__ gsum) {
    int tid = threadIdx.x;
    if (blockIdx.x < BPG) {
        // ---------- bucket histogram ----------
        __shared__ uint32 c[NBUCK];
        int g = blockIdx.y, blk = blockIdx.x;
        const int* e = (g == 0) ? ea : (g == 1) ? ep : en;
        if (tid < NBUCK) c[tid] = 0;
        __syncthreads();
        int base = blk * CHUNK;
        for (int i = tid; i < CHUNK; i += 512)
            atomicAdd(&c[e[N_EDGES + base + i] >> BSH], 1u);
        __syncthreads();
        if (tid < NBUCK) bcnt[((size_t)g * BPG + blk) * NBUCK + tid] = c[tid];
        return;
    }
    int p = (blockIdx.x - BPG) * 3 + blockIdx.y;   // 0..17
    if (p >= 16) return;
    if (p < 8) {
        // ---------- UV tables via parallel scan (512-thread variant) ----------
        __shared__ float w12s[128][16];
        __shared__ float du[128][16];
        __shared__ float dv[128][16];
        __shared__ float pu[16][16], pv[16][16];
        __shared__ float bu[16][16], bv[16][16];
        __shared__ float wsh[128], bsh[128], tss[128], tsh[128];
        __shared__ int osh[128];
        int c0 = p * 16;
        if (tid < 128) {
            float w = W11[tid], b = b11[tid];
            wsh[tid] = w; bsh[tid] = b;
            tsh[tid] = (w != 0.0f) ? (-b / w) : 3.0e38f;
        }
        {
            int r0 = tid >> 4, cc2 = tid & 15;     // r0 0..31
            for (int r = r0; r < 128; r += 32)
                w12s[r][cc2] = W12[r * HID + c0 + cc2];
        }
        __syncthreads();
        if (tid < 128) {
            float t = tsh[tid];
            int rank = 0;
            for (int j = 0; j < 128; ++j) {
                float tj = tsh[j];
                if (tj < t || (tj == t && j < tid)) ++rank;
            }
            tss[rank] = t; osh[rank] = tid;
        }
        __syncthreads();
        if (p == 0 && tid < 128) ts[tid] = tss[tid];
        int c = tid & 15, t = tid >> 4;            // t 0..31; only t<16 active
        if (t < 16) {
            float su = 0.f, sv = 0.f;
#pragma unroll
            for (int m = 0; m < 8; ++m) {
                int j = t * 8 + m;
                int k = osh[j];
                float wk = wsh[k], bk = bsh[k], w12 = w12s[k][c];
                float sg = (wk > 0.f) ? 1.f : ((wk < 0.f) ? -1.f : 0.f);
                du[j][c] = sg * wk * w12;
                dv[j][c] = sg * bk * w12;
                float wb = wsh[j], bb = bsh[j], w12b = w12s[j][c];
                if (wb < 0.f)                     { su += wb * w12b; sv += bb * w12b; }
                else if (wb == 0.f && bb > 0.f)   { sv += bb * w12b; }
            }
            bu[t][c] = su; bv[t][c] = sv;
        }
        __syncthreads();
        if (t < 16) {
            float ru = 0.f, rv = 0.f;
#pragma unroll
            for (int m = 0; m < 8; ++m) {
                int j = t * 8 + m;
                ru += du[j][c]; du[j][c] = ru;
                rv += dv[j][c]; dv[j][c] = rv;
            }
            pu[t][c] = ru; pv[t][c] = rv;
        }
        __syncthreads();
        if (t == 0) {                              // col leader
            float baseu = 0.f;
            float basev = b12[c0 + c];             // bias included
            for (int q = 0; q < 16; ++q) { baseu += bu[q][c]; basev += bv[q][c]; }
            float ou = baseu, ov = basev;
            for (int q = 0; q < 16; ++q) {
                float tu = pu[q][c], tv = pv[q][c];
                pu[q][c] = ou; pv[q][c] = ov;
                ou += tu; ov += tv;
            }
            UV[c0 + c] = baseu; UV[128 + c0 + c] = basev;
        }
        __syncthreads();
        if (t < 16) {
            float offu = pu[t][c], offv = pv[t][c];
#pragma unroll
            for (int m = 0; m < 8; ++m) {
                int j = t * 8 + m;
                UV[(j + 1) * 256 + c0 + c]       = offu + du[j][c];
                UV[(j + 1) * 256 + 128 + c0 + c] = offv + dv[j][c];
            }
        }
    } else if (tid < 256) {
        // ---------- frag-pack W21/W22 ----------
        int idx = (p - 8) * 256 + tid;             // 0..2047
        int tt = idx >> 9, c = (idx >> 6) & 7, l = idx & 63;
        int kbase = tt * 32 + (l >> 4) * 8;
        int colv = c * 16 + (l & 15);
#pragma unroll
        for (int jw = 0; jw < 4; ++jw) {
            float f0 = W21[(kbase + 2 * jw) * HID + colv];
            float f1 = W21[(kbase + 2 * jw + 1) * HID + colv];
            W21p[idx * 4 + jw] = pack2(f0, f1);
            f0 = W22[(kbase + 2 * jw) * HID + colv];
            f1 = W22[(kbase + 2 * jw + 1) * HID + colv];
            W22p[idx * 4 + jw] = pack2(f0, f1);
        }
        if (p == 8)
            for (int i = tid; i < 384; i += 256) gsum[i] = 0.0f;
    }
}

// ---- bucket phase C (fused with scan): partition edges into bucket-major P ----
__launch_bounds__(512)
__global__ void bpart_kernel(const int* __restrict__ ea, const int* __restrict__ ep,
                             const int* __restrict__ en, const uint32* __restrict__ bcnt,
                             uint32* __restrict__ bbase, uint32* __restrict__ P) {
    __shared__ uint32 cur[NBUCK];
    __shared__ uint32 totS[NBUCK];
    __shared__ uint32 sbase[NBUCK + 1];
    int g = blockIdx.y, blk = blockIdx.x, tid = threadIdx.x;
    const int* e = (g == 0) ? ea : (g == 1) ? ep : en;
    if (tid < NBUCK) {
        uint32 myoff = 0, tot = 0;
        const uint32* bc = bcnt + (size_t)g * BPG * NBUCK + tid;
        for (int k = 0; k < BPG; ++k) {
            uint32 v = bc[(size_t)k * NBUCK];
            if (k < blk) myoff += v;
            tot += v;
        }
        cur[tid] = myoff;
        totS[tid] = tot;
    }
    __syncthreads();
    if (tid == 0) {
        uint32 run = 0;
        for (int b2 = 0; b2 < NBUCK; ++b2) { sbase[b2] = run; run += totS[b2]; }
        sbase[NBUCK] = run;   // == N_EDGES
    }
    __syncthreads();
    if (tid < NBUCK) cur[tid] += sbase[tid];
    if (blk == 0 && tid <= NBUCK) bbase[g * 158 + tid] = sbase[tid];
    __syncthreads();
    int base = blk * CHUNK;
    uint32* Pg = P + (size_t)g * N_EDGES;
    for (int i = tid; i < CHUNK; i += 512) {
        int src = e[base + i];
        int dst = e[N_EDGES + base + i];
        uint32 pos = atomicAdd(&cur[dst >> BSH], 1u);
        Pg[pos] = (uint32)src | ((uint32)(dst & 127) << 16);
    }
}

// ---- bucket phase D fused with L1: per-bucket CSR with SELF-EDGE prepended,
//      pad-to-8 WITH sentinel fill (-> zero row), node-major rpe (padded end),
//      + scalar aggregation + pattern-table MLP1 -> X1 ----
__launch_bounds__(256)
__global__ void bcsr_l1_kernel(const uint32* __restrict__ bbase, const uint32* __restrict__ P,
                               const float* __restrict__ xa, const float* __restrict__ xp,
                               const float* __restrict__ xn,
                               const float* __restrict__ ts, const float* __restrict__ UV,
                               int* __restrict__ rpe, uint32* __restrict__ col,
                               uint32* __restrict__ X1) {
    __shared__ uint32 h[128];        // raw counts, then rank cursors
    __shared__ uint32 hraw[128];
    __shared__ uint32 pls[128];      // padded local scan (self+edges, x8)
    __shared__ uint32 wendS;
    __shared__ float accs[128];
    __shared__ float tsh[128];
    __shared__ int pat[128];
    int k = blockIdx.x, g = blockIdx.y, tid = threadIdx.x;
    const float* x = (g == 0) ? xa : (g == 1) ? xp : xn;
    int beg = (int)bbase[g * 158 + k], end = (int)bbase[g * 158 + k + 1];
    int size = end - beg;
    int wbase = beg + k * 1024;      // padded col window base
    int n0 = k * 128;
    int cnt_nodes = NB - n0; if (cnt_nodes > 128) cnt_nodes = 128;
    const uint32 ZOFFB = (uint32)NB << 8;
    if (tid < 128) { h[tid] = 0; accs[tid] = 0.0f; tsh[tid] = ts[tid]; }
    __syncthreads();
    const uint32* Pg = P + (size_t)g * N_EDGES + beg;
    for (int i = tid; i < size; i += 256)
        atomicAdd(&h[(Pg[i] >> 16) & 127], 1u);
    __syncthreads();
    if (tid == 0) {
        uint32 run = 0;
        for (int d = 0; d < 128; ++d) {
            hraw[d] = h[d];
            pls[d] = run;
            run += (h[d] + 8u) & ~7u;   // +1 self edge, pad to 8
        }
        wendS = (uint32)wbase + run;
    }
    __syncthreads();
    uint32* colg = col + (size_t)g * COLCAP;
    if (tid < cnt_nodes) {
        int node = n0 + tid;
        rpe[((size_t)g * NB + node) * 2]     = wbase + (int)pls[tid];
        rpe[((size_t)g * NB + node) * 2 + 1] = wbase + (int)(pls[tid] + ((hraw[tid] + 8u) & ~7u));
        colg[wbase + pls[tid]] = (uint32)node << 8;     // self edge first
        uint32 e0 = pls[tid] + 1u + hraw[tid];
        uint32 e1 = pls[tid] + ((hraw[tid] + 8u) & ~7u);
        for (uint32 q = e0; q < e1; ++q) colg[wbase + q] = ZOFFB;
    } else if (tid < 128) {
        uint32 e0 = pls[tid];
        uint32 e1 = pls[tid] + 8u;
        for (uint32 q = e0; q < e1; ++q) colg[wbase + q] = ZOFFB;
    }
    if (tid < 128) h[tid] = pls[tid] + 1u;   // rank cursors after self
    __syncthreads();
    for (int i = tid; i < size; i += 256) {
        uint32 w = Pg[i];
        int d = (w >> 16) & 127;
        int src = (int)(w & 0xffffu);
        uint32 r = atomicAdd(&h[d], 1u);
        colg[wbase + r] = (uint32)src << 8;   // byte offset src*256
        atomicAdd(&accs[d], x[src]);          // LDS float accumulation
    }
    if (k == 0 && tid < 64)                   // zero row for this graph
        *((uint32*)&X1[((size_t)g * NBP + NB) * 64] + tid) = 0u;
    if (k == NBUCK - 1 && tid < 64)           // tail slack fill (prefetch overrun)
        colg[wendS + tid] = ZOFFB;
    __syncthreads();
    if (tid < cnt_nodes) {
        float s = accs[tid] + x[n0 + tid];
        int lo = 0, hi = 128;
        while (lo < hi) { int mid = (lo + hi) >> 1; if (tsh[mid] < s) lo = mid + 1; else hi = mid; }
        pat[tid] = lo;
        accs[tid] = s;
    }
    __syncthreads();
    uint32* X1g = X1 + ((size_t)g * NBP + n0) * 64;
#pragma unroll 4
    for (int it = 0; it < 32; ++it) {
        int idx = it * 256 + tid;
        int d = idx >> 6, w = idx & 63;
        if (d < cnt_nodes) {
            const float* Up = UV + (size_t)pat[d] * 256;
            float s = accs[d];
            float2 u = *(const float2*)&Up[w * 2];
            float2 v = *(const float2*)&Up[128 + w * 2];
            float r0 = fmaxf(fmaf(s, u.x, v.x), 0.0f);
            float r1 = fmaxf(fmaf(s, u.y, v.y), 0.0f);
            X1g[(size_t)d * 64 + w] = pack2(r0, r1);
        }
    }
}

// ---- L2 aggregation: single launch, 3 phases x 2 tasks x 4 XCDs.
// FOUR nodes per wave (16 lanes: 2 edge slots x 8 words), self-edge in list,
// 4-DEEP pipelined, NO guards (sentinel pads -> zero row), packed f32 adds. ----
__launch_bounds__(256)
__global__ void gather2_kernel(const int* __restrict__ rpe, const uint32* __restrict__ col,
                               const uint32* __restrict__ X1, uint32* __restrict__ H2) {
    int b = blockIdx.x;                        // 0..7511
    int xcd = b & 7, s = b >> 3;               // s 0..938
    int phase = s / 313, slot = s - phase * 313;
    const int gt[3][2] = {{0, 1}, {2, 2}, {0, 1}};
    const int ht[3][2] = {{0, 0}, {0, 1}, {1, 1}};
    int g = gt[phase][xcd >> 2];
    int h = ht[phase][xcd >> 2];
    int nb = slot * 4 + (xcd & 3);             // 0..1251
    if (nb >= 1250) return;
    int tid = threadIdx.x;
    int wave = tid >> 6, lane = tid & 63;
    int node = nb * 16 + wave * 4 + (lane >> 4);
    int l4 = lane & 15;
    int sl = l4 >> 3;                          // edge slot 0..1
    int w = l4 & 7;                            // uint4 index within 128B half-row
    const uint32* colg = col + (size_t)g * COLCAP;
    int2 be = *(const int2*)&rpe[((size_t)g * NB + node) * 2];
    int beg = be.x, end = be.y;                // end = padded end (multiple of 8 len)
    const char* Bg = (const char*)(X1 + (size_t)g * NBP * 64) + h * 128 + w * 16;
    f32x2 A0 = {0.f, 0.f}, A1 = {0.f, 0.f}, A2 = {0.f, 0.f}, A3 = {0.f, 0.f};
    uint32 ca = colg[beg + sl];
    uint32 cb = colg[beg + 2 + sl];
    uint32 cc = colg[beg + 4 + sl];
    uint32 cd = colg[beg + 6 + sl];
    for (int j = beg; j < end; j += 8) {
        uint32 c0 = ca, c1 = cb, c2 = cc, c3 = cd;
        ca = colg[j + 8 + sl];                 // prefetch next group (slack-covered)
        cb = colg[j + 10 + sl];
        cc = colg[j + 12 + sl];
        cd = colg[j + 14 + sl];
        uint4 v0 = *(const uint4*)(Bg + c0);
        uint4 v1 = *(const uint4*)(Bg + c1);
        uint4 v2 = *(const uint4*)(Bg + c2);
        uint4 v3 = *(const uint4*)(Bg + c3);
        A0 += unpk(v0.x); A1 += unpk(v0.y); A2 += unpk(v0.z); A3 += unpk(v0.w);
        A0 += unpk(v1.x); A1 += unpk(v1.y); A2 += unpk(v1.z); A3 += unpk(v1.w);
        A0 += unpk(v2.x); A1 += unpk(v2.y); A2 += unpk(v2.z); A3 += unpk(v2.w);
        A0 += unpk(v3.x); A1 += unpk(v3.y); A2 += unpk(v3.z); A3 += unpk(v3.w);
    }
    float a0 = A0.x, a1 = A0.y, a2 = A1.x, a3 = A1.y;
    float a4 = A2.x, a5 = A2.y, a6 = A3.x, a7 = A3.y;
    a0 += __shfl_xor(a0, 8);
    a1 += __shfl_xor(a1, 8);
    a2 += __shfl_xor(a2, 8);
    a3 += __shfl_xor(a3, 8);
    a4 += __shfl_xor(a4, 8);
    a5 += __shfl_xor(a5, 8);
    a6 += __shfl_xor(a6, 8);
    a7 += __shfl_xor(a7, 8);
    if (sl == 0) {                             // 8 lanes per node store its 128B half
        uint4 o;
        o.x = pack2(a0, a1); o.y = pack2(a2, a3);
        o.z = pack2(a4, a5); o.w = pack2(a6, a7);
        *(uint4*)&H2[(size_t)(g * NB + node) * 64 + h * 32 + w * 4] = o;
    }
}

// ---- MFMA MLP2: x2 = relu(relu(h2@W21+b21)@W22+b22), pool-only ----
__launch_bounds__(256)
__global__ void mlp2_kernel(const uint32* __restrict__ H2,
                            const uint32* __restrict__ W21p, const float* __restrict__ b21,
                            const uint32* __restrict__ W22p, const float* __restrict__ b22,
                            float* __restrict__ gsum) {
    __shared__ uint32 tl[64 * 64];      // t tile, bf16, XOR-swizzled rows of 256B
    __shared__ float psum[HID];
    int g = blockIdx.y;
    int base = blockIdx.x * 64;
    int nvalid = NB - base; if (nvalid > 64) nvalid = 64;
    int tid = threadIdx.x;
    int wave = tid >> 6, l = tid & 63;
    int lq = l >> 4, lr = l & 15;
    if (tid < HID) psum[tid] = 0.0f;
    __syncthreads();

    f32x4 acc[8];
#pragma unroll
    for (int c = 0; c < 8; ++c) acc[c] = (f32x4){0.f, 0.f, 0.f, 0.f};
    int arow = wave * 16 + lr;
    int arowc = (arow < nvalid) ? arow : 0;
    const uint32* h2row = H2 + ((size_t)g * NB + base + arowc) * 64;
#pragma unroll
    for (int t = 0; t < 4; ++t) {
        uint4 av = *(const uint4*)&h2row[t * 16 + lq * 4];
        bf16x8v af = __builtin_bit_cast(bf16x8v, av);
#pragma unroll
        for (int c = 0; c < 8; ++c) {
            uint4 bv = *(const uint4*)&W21p[((t * 8 + c) * 64 + l) * 4];
            acc[c] = __builtin_amdgcn_mfma_f32_16x16x32_bf16(
                af, __builtin_bit_cast(bf16x8v, bv), acc[c], 0, 0, 0);
        }
    }
    unsigned short* tls = (unsigned short*)tl;
#pragma unroll
    for (int c = 0; c < 8; ++c) {
        int colv = c * 16 + lr;
        float bb = b21[colv];
#pragma unroll
        for (int q = 0; q < 4; ++q) {
            int row = wave * 16 + lq * 4 + q;
            float v = fmaxf(acc[c][q] + bb, 0.0f);
            int byte = row * 256 + ((colv * 2) ^ ((row & 7) << 4));
            tls[byte >> 1] = f2bf(v);
        }
    }
    f32x4 acc2[8];
#pragma unroll
    for (int c = 0; c < 8; ++c) acc2[c] = (f32x4){0.f, 0.f, 0.f, 0.f};
#pragma unroll
    for (int t = 0; t < 4; ++t) {
        int rbyte = arow * 256 + (((t * 64 + lq * 16)) ^ ((arow & 7) << 4));
        uint4 av = *(const uint4*)((const char*)tl + rbyte);
        bf16x8v af = __builtin_bit_cast(bf16x8v, av);
#pragma unroll
        for (int c = 0; c < 8; ++c) {
            uint4 bv = *(const uint4*)&W22p[((t * 8 + c) * 64 + l) * 4];
            acc2[c] = __builtin_amdgcn_mfma_f32_16x16x32_bf16(
                af, __builtin_bit_cast(bf16x8v, bv), acc2[c], 0, 0, 0);
        }
    }
#pragma unroll
    for (int c = 0; c < 8; ++c) {
        float bb = b22[c * 16 + lr];
        float s = 0.0f;
#pragma unroll
        for (int q = 0; q < 4; ++q) {
            int row = wave * 16 + lq * 4 + q;
            float v = fmaxf(acc2[c][q] + bb, 0.0f);
            s += (row < nvalid) ? v : 0.0f;
        }
        s += __shfl_xor(s, 16);
        s += __shfl_xor(s, 32);
        if (lq == 0) atomicAdd(&psum[c * 16 + lr], s);
    }
    __syncthreads();
    if (tid < HID) atomicAdd(&gsum[g * HID + tid], psum[tid]);
}

// ---- triplet head ----
__global__ void final_kernel(const float* __restrict__ gsum, const float* __restrict__ Wf,
                             const float* __restrict__ bf, float* __restrict__ out) {
    int tid = threadIdx.x;  // 384
    int g = tid >> 7;
    int o = tid & 127;
    float acc = bf[o];
    for (int k = 0; k < HID; ++k)
        acc += gsum[g * HID + k] * Wf[k * HID + o];
    out[g * HID + o] = acc;
}

extern "C" void kernel_launch(void* const* d_in, const int* in_sizes, int n_in,
                              void* d_out, int out_size, void* d_ws, size_t ws_size,
                              hipStream_t stream) {
    const float* xa = (const float*)d_in[0];
    const int*   ea = (const int*)d_in[1];
    const float* xp = (const float*)d_in[2];
    const int*   ep = (const int*)d_in[3];
    const float* xn = (const float*)d_in[4];
    const int*   en = (const int*)d_in[5];
    const float* W11 = (const float*)d_in[6];
    const float* b11 = (const float*)d_in[7];
    const float* W12 = (const float*)d_in[8];
    const float* b12 = (const float*)d_in[9];
    const float* W21 = (const float*)d_in[10];
    const float* b21 = (const float*)d_in[11];
    const float* W22 = (const float*)d_in[12];
    const float* b22 = (const float*)d_in[13];
    const float* Wf  = (const float*)d_in[14];
    const float* bf  = (const float*)d_in[15];

    float*  ws    = (float*)d_ws;
    uint32* P     = (uint32*)(ws + P_OFF);
    uint32* bcnt  = (uint32*)(ws + BCNT_OFF);
    uint32* bbase = (uint32*)(ws + BBASE_OFF);
    uint32* X1    = (uint32*)(ws + X1_OFF);
    uint32* H2    = (uint32*)(ws + H2_OFF);
    uint32* col   = (uint32*)(ws + COL_OFF);
    int*    rpe   = (int*)(ws + RPE_OFF);
    float*  gsum  = ws + GSUM_OFF;
    float*  ts    = ws + TS_OFF;
    float*  UV    = ws + UV_OFF;
    uint32* W21p  = (uint32*)(ws + W21P_OFF);
    uint32* W22p  = (uint32*)(ws + W22P_OFF);
    float*  out   = (float*)d_out;

    bhist_prep_kernel<<<dim3(BPG + 6, 3), 512, 0, stream>>>(
        ea, ep, en, bcnt, W11, b11, W12, b12, W21, W22, ts, UV, W21p, W22p, gsum);
    bpart_kernel<<<dim3(BPG, 3), 512, 0, stream>>>(ea, ep, en, bcnt, bbase, P);
    bcsr_l1_kernel<<<dim3(NBUCK, 3), 256, 0, stream>>>(bbase, P, xa, xp, xn, ts, UV, rpe, col, X1);
    gather2_kernel<<<7512, 256, 0, stream>>>(rpe, col, X1, H2);
    mlp2_kernel<<<dim3(NBLK64, 3), 256, 0, stream>>>(H2, W21p, b21, W22p, b22, gsum);
    final_kernel<<<1, 384, 0, stream>>>(gsum, Wf, bf, out);
}